// Round 4
// baseline (690.139 us; speedup 1.0000x reference)
//
#include <hip/hip_runtime.h>
#include <hip/hip_bf16.h>
#include <math.h>

// ---------------------------------------------------------------------------
// CgpHmmCell forward: 512 seqs x 2048 steps x 25-state HMM (23 live states;
// states 23/24 emit only 'X' which never occurs in tokens in [0,4)).
//
// Fused design: one block = one sequence. 512 threads = 16 groups x 32 lanes;
// group = chunk of 128 steps, lane = basis row. Chunk transfer matrices are
// kept in LDS (bf16 values + fp32 log-scale); wave 0 folds them after a
// block barrier. No T round-trip through HBM (was 17.6 MB write + 18 MB
// latency-bound read in round 3).
//
// ws layout (floats): WS_AW=0: 21 packed A-weights | WS_I=32: init probs |
//                     WS_BT=64: Bt[216][32] (pitch 32, states 0..24)
// ---------------------------------------------------------------------------

#define NSTATES 25
#define NLIVE   23
#define NFLAT   216
#define TLEN    2048
#define NSEQ    512
#define CHUNKS  16
#define CLEN    128

#define WS_AW 0
#define WS_I  32
#define WS_BT 64

// ---------------------------------------------------------------------------
// Compile-time emission map: WMAP[state*216+flat] = k-index into wE,
// -1 = non-trainable (logit 1.0), -2 = absent. (Validated: absmax 0.0.)
// ---------------------------------------------------------------------------
struct WMap { short m[NSTATES * NFLAT]; };

constexpr WMap make_wmap() {
  WMap w{};
  for (int i = 0; i < NSTATES * NFLAT; i++) w.m[i] = -2;
  const unsigned char ST[29] = {0,1,2,3,4,5,6,7,8,9,10,11,11,12,12,12,13,
                                14,15,16,17,18,19,20,21,22,23,23,24};
  const unsigned char M1[29] = {0x1F,0x1F,0x1F,0x11,0x18,0x14,0x1F,0x1F,0x1F,
                                0x1F,0x0F,0x0F,0x0F,0x08,0x08,0x08,0x0F,
                                0x1F,0x1F,0x1F,0x1F,0x1F,0x1F,0x1F,0x1F,0x1F,
                                0x0F,0x0F,0x20};
  const unsigned char M2[29] = {0x1F,0x1F,0x11,0x18,0x14,0x1F,0x1F,0x1F,0x1F,
                                0x1F,0x0F,0x08,0x08,0x01,0x01,0x04,0x0F,
                                0x1F,0x1F,0x1F,0x1F,0x1F,0x1F,0x1F,0x1F,0x1F,
                                0x0F,0x20,0x20};
  const unsigned char M3[29] = {0x0F,0x01,0x08,0x04,0x0F,0x0F,0x0F,0x0F,0x0F,
                                0x0F,0x08,0x01,0x04,0x01,0x04,0x01,0x0F,
                                0x0F,0x0F,0x0F,0x0F,0x0F,0x0F,0x0F,0x0F,0x0F,
                                0x20,0x20,0x20};
  const unsigned char TR[29] = {1,1,1,0,1,1,1,1,1,1,1,1,1,0,0,0,1,
                                1,1,1,1,1,1,1,1,1,1,1,0};
  int k = 0;
  for (int s = 0; s < 29; s++) {
    for (int c1 = 0; c1 < 6; c1++) {
      if (!((M1[s] >> c1) & 1)) continue;
      for (int c2 = 0; c2 < 6; c2++) {
        if (!((M2[s] >> c2) & 1)) continue;
        if (c1 != 4 && c2 == 4) continue;  // pad-4 only as prefix (ORDER=2)
        for (int c3 = 0; c3 < 6; c3++) {
          if (!((M3[s] >> c3) & 1)) continue;
          w.m[ST[s] * NFLAT + c1 * 36 + c2 * 6 + c3] =
              TR[s] ? (short)(k++) : (short)-1;
        }
      }
    }
  }
  return w;
}
__device__ __constant__ WMap WMAP = make_wmap();

__device__ __forceinline__ unsigned short f2bf(float x) {  // RNE
  unsigned int u = __float_as_uint(x);
  u += 0x7fffu + ((u >> 16) & 1u);
  return (unsigned short)(u >> 16);
}
__device__ __forceinline__ float bf2f(unsigned short b) {
  return __uint_as_float(((unsigned int)b) << 16);
}

// ---------------------------------------------------------------------------
// Setup: 26 blocks x 64. Blocks 0..24: emission row st (exp, wave-reduce sum,
// write Bt[flat][st]). Block 25: A-weights + I.
// ---------------------------------------------------------------------------
__global__ __launch_bounds__(64)
void setup_kernel(const float* __restrict__ wT, const float* __restrict__ wE,
                  const float* __restrict__ wI, float* __restrict__ ws) {
  const int st = blockIdx.x;
  const int lane = threadIdx.x;

  if (st < NSTATES) {
    float e[4];
    float part = 0.0f;
    int cnt = 0;
    for (int c = lane; c < NFLAT; c += 64, cnt++) {
      short m = WMAP.m[st * NFLAT + c];
      float v = 0.0f;
      if (m == -1) v = expf(1.0f);
      else if (m >= 0) v = expf(wE[m]);
      e[cnt] = v;
      part += v;
    }
    #pragma unroll
    for (int m = 1; m < 64; m <<= 1) part += __shfl_xor(part, m, 64);
    float inv = 1.0f / part;
    cnt = 0;
    for (int c = lane; c < NFLAT; c += 64, cnt++)
      ws[WS_BT + c * 32 + st] = e[cnt] * inv;
  } else {
    if (lane == 0) {
      // softmax of multi-entry A rows -> 21 packed weights (validated)
      const float w0 = wT[0], w1 = wT[1], w2 = wT[2], w3 = wT[3], w4 = wT[4];
      const float w5 = wT[5], w6 = wT[6], w7 = wT[7], w8 = wT[8], w9 = wT[9];
      { float e0 = expf(1.0f - w0), e1 = expf(w0), is = 1.0f / (e0 + e1);
        ws[WS_AW + 0] = e0 * is; ws[WS_AW + 1] = e1 * is; }
      { float e4 = expf(w1), e14 = expf(w3);
        float e7 = expf(1.0f - w9 * w9), e10 = expf(1.0f - w9 * w9 * w9);
        float is = 1.0f / (e4 + e14 + e7 + e10);
        ws[WS_AW + 2] = e4 * is;  ws[WS_AW + 3] = e14 * is;
        ws[WS_AW + 4] = e7 * is;  ws[WS_AW + 5] = e10 * is; }
      { float e7 = expf(w2), e17 = expf(w4), e10 = expf(1.0f - w9 * w9);
        float is = 1.0f / (e7 + e17 + e10);
        ws[WS_AW + 6] = e7 * is; ws[WS_AW + 7] = e17 * is; ws[WS_AW + 8] = e10 * is; }
      { float e20 = expf(w5), e10 = expf(1.0f - w5), is = 1.0f / (e20 + e10);
        ws[WS_AW + 9] = e20 * is; ws[WS_AW + 10] = e10 * is; }
      ws[WS_AW + 11] = 0.5f; ws[WS_AW + 12] = 0.5f;   // row 13
      { float e4 = expf(w6), e14 = expf(1.0f - w6), is = 1.0f / (e4 + e14);
        ws[WS_AW + 13] = e4 * is; ws[WS_AW + 14] = e14 * is; }
      { float e7 = expf(w7), e17 = expf(1.0f - w7), is = 1.0f / (e7 + e17);
        ws[WS_AW + 15] = e7 * is; ws[WS_AW + 16] = e17 * is; }
      { float e10 = expf(w8), e20 = expf(1.0f - w8), is = 1.0f / (e10 + e20);
        ws[WS_AW + 17] = e10 * is; ws[WS_AW + 18] = e20 * is; }
      ws[WS_AW + 19] = 0.5f; ws[WS_AW + 20] = 0.5f;
    } else if (lane == 32) {
      float e[9], s = 0.0f;
      for (int i = 0; i < 9; i++) { e[i] = expf(wI[i]); s += e[i]; }
      float inv = 1.0f / s;
      for (int i = 0; i < 9; i++) ws[WS_I + i] = e[i] * inv;
      for (int i = 9; i < 32; i++) ws[WS_I + i] = 0.0f;
    }
  }
}

// ---------------------------------------------------------------------------
// One HMM step over the 23 live states (validated round 3).
// ---------------------------------------------------------------------------
__device__ __forceinline__ void hmm_step(float (&a)[NLIVE], const float (&w)[21],
                                         const float* __restrict__ bt, int flat) {
  const float* er = bt + (flat << 5);
  float4 e0 = *(const float4*)(er + 0);
  float4 e1 = *(const float4*)(er + 4);
  float4 e2 = *(const float4*)(er + 8);
  float4 e3 = *(const float4*)(er + 12);
  float4 e4 = *(const float4*)(er + 16);
  float4 e5 = *(const float4*)(er + 20);

  float n0  = a[0]*w[0];
  float n1  = a[0]*w[1];
  float n4  = a[3]*w[2]  + a[16]*w[13];
  float n7  = a[3]*w[4]  + a[6]*w[6]  + a[19]*w[15];
  float n10 = a[3]*w[5]  + a[6]*w[8]  + a[9]*w[10] + a[22]*w[17];
  float n13 = a[12]      + a[13]*w[11];
  float n14 = a[3]*w[3]  + a[16]*w[14];
  float n17 = a[6]*w[7]  + a[19]*w[16];
  float n20 = a[9]*w[9]  + a[22]*w[18];
  float o2 = a[1],  o3 = a[2],  o5 = a[4],  o6 = a[5];
  float o8 = a[7],  o9 = a[8],  o11 = a[10], o12 = a[11];
  float o15 = a[14], o16 = a[15], o18 = a[17], o19 = a[18];
  float o21 = a[20], o22 = a[21];

  a[0] = n0 * e0.x;  a[1] = n1 * e0.y;  a[2] = o2 * e0.z;  a[3] = o3 * e0.w;
  a[4] = n4 * e1.x;  a[5] = o5 * e1.y;  a[6] = o6 * e1.z;  a[7] = n7 * e1.w;
  a[8] = o8 * e2.x;  a[9] = o9 * e2.y;  a[10] = n10 * e2.z; a[11] = o11 * e2.w;
  a[12] = o12 * e3.x; a[13] = n13 * e3.y; a[14] = n14 * e3.z; a[15] = o15 * e3.w;
  a[16] = o16 * e4.x; a[17] = n17 * e4.y; a[18] = o18 * e4.z; a[19] = o19 * e4.w;
  a[20] = n20 * e5.x; a[21] = o21 * e5.y; a[22] = o22 * e5.z;
}

__device__ __forceinline__ void renorm(float (&a)[NLIVE], float& L) {
  float s = (((a[0]+a[1])+(a[2]+a[3])) + ((a[4]+a[5])+(a[6]+a[7])))
          + (((a[8]+a[9])+(a[10]+a[11])) + ((a[12]+a[13])+(a[14]+a[15])))
          + (((a[16]+a[17])+(a[18]+a[19])) + ((a[20]+a[21])+a[22]));
  if (s > 0.0f) {
    L += __logf(s);
    float r = __fdividef(1.0f, s);
    #pragma unroll
    for (int j = 0; j < NLIVE; j++) a[j] *= r;
  } else {
    L = -3.0e38f;  // row died; stays dead
  }
}

// ---------------------------------------------------------------------------
// Fused rows + combine: block = one sequence; 16 groups x 32 lanes.
// ---------------------------------------------------------------------------
__global__ __launch_bounds__(512, 6)
void rows_kernel(const float* __restrict__ ws, const int* __restrict__ tokens,
                 float* __restrict__ out) {
  __shared__ float sBt[NFLAT * 32];                 // 27648 B
  __shared__ unsigned short sT[CHUNKS * NLIVE * 24];// 17664 B (bf16 values)
  __shared__ float sL[CHUNKS * NLIVE];              // 1472 B (fp32 log-scales)

  for (int i = threadIdx.x; i < NFLAT * 32; i += 512) sBt[i] = ws[WS_BT + i];
  __syncthreads();

  const int seq   = blockIdx.x;
  const int chunk = threadIdx.x >> 5;
  const int row   = threadIdx.x & 31;
  const int* trow = tokens + (size_t)seq * TLEN;
  const int t0    = chunk * CLEN;

  float w[21];
  #pragma unroll
  for (int i = 0; i < 21; i++) w[i] = ws[WS_AW + i];  // uniform -> SGPRs

  float a[NLIVE];
  #pragma unroll
  for (int j = 0; j < NLIVE; j++) a[j] = 0.0f;
  if (row < NLIVE) a[row] = 1.0f;
  float L = 0.0f;

  int p1, p2;
  int4 q0 = *(const int4*)(trow + t0);
  int4 q1 = *(const int4*)(trow + t0 + 4);

  int b = 0;
  if (chunk == 0) {
    // steps t = 1..7 (t = 0 is folded into the combine's init)
    p1 = 4; p2 = q0.x;
    int tb[8] = {q0.x, q0.y, q0.z, q0.w, q1.x, q1.y, q1.z, q1.w};
    q0 = *(const int4*)(trow + 8);
    q1 = *(const int4*)(trow + 12);
    #pragma unroll
    for (int u = 1; u < 8; u++) {
      int nt = tb[u];
      hmm_step(a, w, sBt, p1 * 36 + p2 * 6 + nt);
      p1 = p2; p2 = nt;
    }
    renorm(a, L);
    b = 1;
  } else {
    int2 pp = *(const int2*)(trow + t0 - 2);   // 8B-aligned (t0 mult of 128)
    p1 = pp.x; p2 = pp.y;
  }

  for (; b < CLEN / 8; b++) {
    int tb[8] = {q0.x, q0.y, q0.z, q0.w, q1.x, q1.y, q1.z, q1.w};
    if (b < CLEN / 8 - 1) {
      q0 = *(const int4*)(trow + t0 + (b + 1) * 8);
      q1 = *(const int4*)(trow + t0 + (b + 1) * 8 + 4);
    }
    #pragma unroll
    for (int u = 0; u < 8; u++) {
      int nt = tb[u];
      hmm_step(a, w, sBt, p1 * 36 + p2 * 6 + nt);
      p1 = p2; p2 = nt;
    }
    renorm(a, L);
  }

  // stash chunk matrix row in LDS (bf16 values, fp32 L)
  if (row < NLIVE) {
    const int base = (chunk * NLIVE + row) * 24;
    #pragma unroll
    for (int k = 0; k < 11; k++) {
      ushort2 p; p.x = f2bf(a[2 * k]); p.y = f2bf(a[2 * k + 1]);
      *(ushort2*)&sT[base + 2 * k] = p;
    }
    { ushort2 p; p.x = f2bf(a[22]); p.y = 0; *(ushort2*)&sT[base + 22] = p; }
    sL[chunk * NLIVE + row] = L;
  }
  __syncthreads();

  // ---- combine (wave 0 only): fold 16 chunk matrices, lane j = column j ----
  if (threadIdx.x < 64) {
    const int lane = threadIdx.x;
    const bool act = (lane < NLIVE);
    const int jc   = act ? lane : 0;

    const int tok0 = trow[0];
    const int flat0 = 168 + tok0;   // tp context (4,4,tok0)

    float v = act ? ws[WS_I + lane] * sBt[flat0 * 32 + lane] : 0.0f;
    float s = v;
    #pragma unroll
    for (int m = 1; m < 32; m <<= 1) s += __shfl_xor(s, m, 32);
    float ll = __logf(s);
    v = act ? v * __fdividef(1.0f, s) : 0.0f;

    for (int c = 0; c < CHUNKS; c++) {
      float Lj  = act ? sL[c * NLIVE + lane] : -3.0e38f;
      float key = (act && v > 0.0f) ? Lj : -3.0e38f;
      float mx = key;
      #pragma unroll
      for (int m = 1; m < 32; m <<= 1) mx = fmaxf(mx, __shfl_xor(mx, m, 32));
      float wgt = (act && v > 0.0f) ? v * __expf(Lj - mx) : 0.0f;

      float nv = 0.0f;
      #pragma unroll
      for (int r = 0; r < NLIVE; r++) {
        float wr = __shfl(wgt, r, 64);
        nv += wr * bf2f(sT[(c * NLIVE + r) * 24 + jc]);
      }
      float nva = act ? nv : 0.0f;
      float s2 = nva;
      #pragma unroll
      for (int m = 1; m < 32; m <<= 1) s2 += __shfl_xor(s2, m, 32);
      ll += mx + __logf(s2);
      v = act ? nv * __fdividef(1.0f, s2) : 0.0f;
    }

    if (lane == 0) out[seq] = ll;
  }
}

// ---------------------------------------------------------------------------
extern "C" void kernel_launch(void* const* d_in, const int* in_sizes, int n_in,
                              void* d_out, int out_size, void* d_ws, size_t ws_size,
                              hipStream_t stream) {
  const float* wT = (const float*)d_in[0];   // transition_kernel (10)
  const float* wE = (const float*)d_in[1];   // emission_kernel (5400)
  const float* wI = (const float*)d_in[2];   // init_kernel (25)
  const int* tokens = (const int*)d_in[3];   // (512, 2048) int32
  float* out = (float*)d_out;                // (512,) float32
  float* ws = (float*)d_ws;                  // ~28 KB used

  setup_kernel<<<26, 64, 0, stream>>>(wT, wE, wI, ws);
  rows_kernel<<<NSEQ, 512, 0, stream>>>(ws, tokens, out);
}

// Round 5
// 148.415 us; speedup vs baseline: 4.6501x; 4.6501x over previous
//
#include <hip/hip_runtime.h>
#include <hip/hip_bf16.h>
#include <math.h>

// ---------------------------------------------------------------------------
// CgpHmmCell forward: 512 seqs x 2048 steps x 25-state HMM (23 live states;
// states 23/24 emit only 'X' which never occurs in tokens in [0,4)).
//
// Fused design: one block = one sequence. 512 threads = 16 groups x 32 lanes;
// group = chunk of 128 steps, lane = basis row. Chunk transfer matrices are
// kept in LDS (bf16 values + fp32 log-scale); wave 0 folds them after a
// block barrier. No T round-trip through HBM.
//
// NOTE round-4 lesson: __launch_bounds__(512, 6) clamped VGPRs to 40 and
// spilled the whole live set to scratch (3.1 GB HBM traffic, 4x slowdown).
// The kernel needs ~68 VGPRs; leave the allocator unconstrained.
//
// ws layout (floats): WS_AW=0: 21 packed A-weights | WS_I=32: init probs |
//                     WS_BT=64: Bt[216][32] (pitch 32, states 0..24)
// ---------------------------------------------------------------------------

#define NSTATES 25
#define NLIVE   23
#define NFLAT   216
#define TLEN    2048
#define NSEQ    512
#define CHUNKS  16
#define CLEN    128

#define WS_AW 0
#define WS_I  32
#define WS_BT 64

// ---------------------------------------------------------------------------
// Compile-time emission map: WMAP[state*216+flat] = k-index into wE,
// -1 = non-trainable (logit 1.0), -2 = absent. (Validated: absmax 0.0.)
// ---------------------------------------------------------------------------
struct WMap { short m[NSTATES * NFLAT]; };

constexpr WMap make_wmap() {
  WMap w{};
  for (int i = 0; i < NSTATES * NFLAT; i++) w.m[i] = -2;
  const unsigned char ST[29] = {0,1,2,3,4,5,6,7,8,9,10,11,11,12,12,12,13,
                                14,15,16,17,18,19,20,21,22,23,23,24};
  const unsigned char M1[29] = {0x1F,0x1F,0x1F,0x11,0x18,0x14,0x1F,0x1F,0x1F,
                                0x1F,0x0F,0x0F,0x0F,0x08,0x08,0x08,0x0F,
                                0x1F,0x1F,0x1F,0x1F,0x1F,0x1F,0x1F,0x1F,0x1F,
                                0x0F,0x0F,0x20};
  const unsigned char M2[29] = {0x1F,0x1F,0x11,0x18,0x14,0x1F,0x1F,0x1F,0x1F,
                                0x1F,0x0F,0x08,0x08,0x01,0x01,0x04,0x0F,
                                0x1F,0x1F,0x1F,0x1F,0x1F,0x1F,0x1F,0x1F,0x1F,
                                0x0F,0x20,0x20};
  const unsigned char M3[29] = {0x0F,0x01,0x08,0x04,0x0F,0x0F,0x0F,0x0F,0x0F,
                                0x0F,0x08,0x01,0x04,0x01,0x04,0x01,0x0F,
                                0x0F,0x0F,0x0F,0x0F,0x0F,0x0F,0x0F,0x0F,0x0F,
                                0x20,0x20,0x20};
  const unsigned char TR[29] = {1,1,1,0,1,1,1,1,1,1,1,1,1,0,0,0,1,
                                1,1,1,1,1,1,1,1,1,1,1,0};
  int k = 0;
  for (int s = 0; s < 29; s++) {
    for (int c1 = 0; c1 < 6; c1++) {
      if (!((M1[s] >> c1) & 1)) continue;
      for (int c2 = 0; c2 < 6; c2++) {
        if (!((M2[s] >> c2) & 1)) continue;
        if (c1 != 4 && c2 == 4) continue;  // pad-4 only as prefix (ORDER=2)
        for (int c3 = 0; c3 < 6; c3++) {
          if (!((M3[s] >> c3) & 1)) continue;
          w.m[ST[s] * NFLAT + c1 * 36 + c2 * 6 + c3] =
              TR[s] ? (short)(k++) : (short)-1;
        }
      }
    }
  }
  return w;
}
__device__ __constant__ WMap WMAP = make_wmap();

__device__ __forceinline__ unsigned short f2bf(float x) {  // RNE
  unsigned int u = __float_as_uint(x);
  u += 0x7fffu + ((u >> 16) & 1u);
  return (unsigned short)(u >> 16);
}
__device__ __forceinline__ float bf2f(unsigned short b) {
  return __uint_as_float(((unsigned int)b) << 16);
}

// ---------------------------------------------------------------------------
// Setup: 26 blocks x 64. Blocks 0..24: emission row st (exp, wave-reduce sum,
// write Bt[flat][st]). Block 25: A-weights + I.
// ---------------------------------------------------------------------------
__global__ __launch_bounds__(64)
void setup_kernel(const float* __restrict__ wT, const float* __restrict__ wE,
                  const float* __restrict__ wI, float* __restrict__ ws) {
  const int st = blockIdx.x;
  const int lane = threadIdx.x;

  if (st < NSTATES) {
    float e[4];
    float part = 0.0f;
    int cnt = 0;
    for (int c = lane; c < NFLAT; c += 64, cnt++) {
      short m = WMAP.m[st * NFLAT + c];
      float v = 0.0f;
      if (m == -1) v = expf(1.0f);
      else if (m >= 0) v = expf(wE[m]);
      e[cnt] = v;
      part += v;
    }
    #pragma unroll
    for (int m = 1; m < 64; m <<= 1) part += __shfl_xor(part, m, 64);
    float inv = 1.0f / part;
    cnt = 0;
    for (int c = lane; c < NFLAT; c += 64, cnt++)
      ws[WS_BT + c * 32 + st] = e[cnt] * inv;
  } else {
    if (lane == 0) {
      // softmax of multi-entry A rows -> 21 packed weights (validated)
      const float w0 = wT[0], w1 = wT[1], w2 = wT[2], w3 = wT[3], w4 = wT[4];
      const float w5 = wT[5], w6 = wT[6], w7 = wT[7], w8 = wT[8], w9 = wT[9];
      { float e0 = expf(1.0f - w0), e1 = expf(w0), is = 1.0f / (e0 + e1);
        ws[WS_AW + 0] = e0 * is; ws[WS_AW + 1] = e1 * is; }
      { float e4 = expf(w1), e14 = expf(w3);
        float e7 = expf(1.0f - w9 * w9), e10 = expf(1.0f - w9 * w9 * w9);
        float is = 1.0f / (e4 + e14 + e7 + e10);
        ws[WS_AW + 2] = e4 * is;  ws[WS_AW + 3] = e14 * is;
        ws[WS_AW + 4] = e7 * is;  ws[WS_AW + 5] = e10 * is; }
      { float e7 = expf(w2), e17 = expf(w4), e10 = expf(1.0f - w9 * w9);
        float is = 1.0f / (e7 + e17 + e10);
        ws[WS_AW + 6] = e7 * is; ws[WS_AW + 7] = e17 * is; ws[WS_AW + 8] = e10 * is; }
      { float e20 = expf(w5), e10 = expf(1.0f - w5), is = 1.0f / (e20 + e10);
        ws[WS_AW + 9] = e20 * is; ws[WS_AW + 10] = e10 * is; }
      ws[WS_AW + 11] = 0.5f; ws[WS_AW + 12] = 0.5f;   // row 13
      { float e4 = expf(w6), e14 = expf(1.0f - w6), is = 1.0f / (e4 + e14);
        ws[WS_AW + 13] = e4 * is; ws[WS_AW + 14] = e14 * is; }
      { float e7 = expf(w7), e17 = expf(1.0f - w7), is = 1.0f / (e7 + e17);
        ws[WS_AW + 15] = e7 * is; ws[WS_AW + 16] = e17 * is; }
      { float e10 = expf(w8), e20 = expf(1.0f - w8), is = 1.0f / (e10 + e20);
        ws[WS_AW + 17] = e10 * is; ws[WS_AW + 18] = e20 * is; }
      ws[WS_AW + 19] = 0.5f; ws[WS_AW + 20] = 0.5f;
    } else if (lane == 32) {
      float e[9], s = 0.0f;
      for (int i = 0; i < 9; i++) { e[i] = expf(wI[i]); s += e[i]; }
      float inv = 1.0f / s;
      for (int i = 0; i < 9; i++) ws[WS_I + i] = e[i] * inv;
      for (int i = 9; i < 32; i++) ws[WS_I + i] = 0.0f;
    }
  }
}

// ---------------------------------------------------------------------------
// One HMM step over the 23 live states (validated round 3).
// ---------------------------------------------------------------------------
__device__ __forceinline__ void hmm_step(float (&a)[NLIVE], const float (&w)[21],
                                         const float* __restrict__ bt, int flat) {
  const float* er = bt + (flat << 5);
  float4 e0 = *(const float4*)(er + 0);
  float4 e1 = *(const float4*)(er + 4);
  float4 e2 = *(const float4*)(er + 8);
  float4 e3 = *(const float4*)(er + 12);
  float4 e4 = *(const float4*)(er + 16);
  float4 e5 = *(const float4*)(er + 20);

  float n0  = a[0]*w[0];
  float n1  = a[0]*w[1];
  float n4  = a[3]*w[2]  + a[16]*w[13];
  float n7  = a[3]*w[4]  + a[6]*w[6]  + a[19]*w[15];
  float n10 = a[3]*w[5]  + a[6]*w[8]  + a[9]*w[10] + a[22]*w[17];
  float n13 = a[12]      + a[13]*w[11];
  float n14 = a[3]*w[3]  + a[16]*w[14];
  float n17 = a[6]*w[7]  + a[19]*w[16];
  float n20 = a[9]*w[9]  + a[22]*w[18];
  float o2 = a[1],  o3 = a[2],  o5 = a[4],  o6 = a[5];
  float o8 = a[7],  o9 = a[8],  o11 = a[10], o12 = a[11];
  float o15 = a[14], o16 = a[15], o18 = a[17], o19 = a[18];
  float o21 = a[20], o22 = a[21];

  a[0] = n0 * e0.x;  a[1] = n1 * e0.y;  a[2] = o2 * e0.z;  a[3] = o3 * e0.w;
  a[4] = n4 * e1.x;  a[5] = o5 * e1.y;  a[6] = o6 * e1.z;  a[7] = n7 * e1.w;
  a[8] = o8 * e2.x;  a[9] = o9 * e2.y;  a[10] = n10 * e2.z; a[11] = o11 * e2.w;
  a[12] = o12 * e3.x; a[13] = n13 * e3.y; a[14] = n14 * e3.z; a[15] = o15 * e3.w;
  a[16] = o16 * e4.x; a[17] = n17 * e4.y; a[18] = o18 * e4.z; a[19] = o19 * e4.w;
  a[20] = n20 * e5.x; a[21] = o21 * e5.y; a[22] = o22 * e5.z;
}

__device__ __forceinline__ void renorm(float (&a)[NLIVE], float& L) {
  float s = (((a[0]+a[1])+(a[2]+a[3])) + ((a[4]+a[5])+(a[6]+a[7])))
          + (((a[8]+a[9])+(a[10]+a[11])) + ((a[12]+a[13])+(a[14]+a[15])))
          + (((a[16]+a[17])+(a[18]+a[19])) + ((a[20]+a[21])+a[22]));
  if (s > 0.0f) {
    L += __logf(s);
    float r = __fdividef(1.0f, s);
    #pragma unroll
    for (int j = 0; j < NLIVE; j++) a[j] *= r;
  } else {
    L = -3.0e38f;  // row died; stays dead
  }
}

// ---------------------------------------------------------------------------
// Fused rows + combine: block = one sequence; 16 groups x 32 lanes.
// __launch_bounds__(512) ONLY — no min-waves arg (round-4 spill lesson).
// ---------------------------------------------------------------------------
__global__ __launch_bounds__(512)
void rows_kernel(const float* __restrict__ ws, const int* __restrict__ tokens,
                 float* __restrict__ out) {
  __shared__ float sBt[NFLAT * 32];                 // 27648 B
  __shared__ unsigned short sT[CHUNKS * NLIVE * 24];// 17664 B (bf16 values)
  __shared__ float sL[CHUNKS * NLIVE];              // 1472 B (fp32 log-scales)

  for (int i = threadIdx.x; i < NFLAT * 32; i += 512) sBt[i] = ws[WS_BT + i];
  __syncthreads();

  const int seq   = blockIdx.x;
  const int chunk = threadIdx.x >> 5;
  const int row   = threadIdx.x & 31;
  const int* trow = tokens + (size_t)seq * TLEN;
  const int t0    = chunk * CLEN;

  float w[21];
  #pragma unroll
  for (int i = 0; i < 21; i++) w[i] = ws[WS_AW + i];  // uniform -> SGPRs

  float a[NLIVE];
  #pragma unroll
  for (int j = 0; j < NLIVE; j++) a[j] = 0.0f;
  if (row < NLIVE) a[row] = 1.0f;
  float L = 0.0f;

  int p1, p2;
  int4 q0 = *(const int4*)(trow + t0);
  int4 q1 = *(const int4*)(trow + t0 + 4);

  int b = 0;
  if (chunk == 0) {
    // steps t = 1..7 (t = 0 is folded into the combine's init)
    p1 = 4; p2 = q0.x;
    int tb[8] = {q0.x, q0.y, q0.z, q0.w, q1.x, q1.y, q1.z, q1.w};
    q0 = *(const int4*)(trow + 8);
    q1 = *(const int4*)(trow + 12);
    #pragma unroll
    for (int u = 1; u < 8; u++) {
      int nt = tb[u];
      hmm_step(a, w, sBt, p1 * 36 + p2 * 6 + nt);
      p1 = p2; p2 = nt;
    }
    renorm(a, L);
    b = 1;
  } else {
    int2 pp = *(const int2*)(trow + t0 - 2);   // 8B-aligned (t0 mult of 128)
    p1 = pp.x; p2 = pp.y;
  }

  for (; b < CLEN / 8; b++) {
    int tb[8] = {q0.x, q0.y, q0.z, q0.w, q1.x, q1.y, q1.z, q1.w};
    if (b < CLEN / 8 - 1) {
      q0 = *(const int4*)(trow + t0 + (b + 1) * 8);
      q1 = *(const int4*)(trow + t0 + (b + 1) * 8 + 4);
    }
    #pragma unroll
    for (int u = 0; u < 8; u++) {
      int nt = tb[u];
      hmm_step(a, w, sBt, p1 * 36 + p2 * 6 + nt);
      p1 = p2; p2 = nt;
    }
    renorm(a, L);
  }

  // stash chunk matrix row in LDS (bf16 values, fp32 L)
  if (row < NLIVE) {
    const int base = (chunk * NLIVE + row) * 24;
    #pragma unroll
    for (int k = 0; k < 11; k++) {
      ushort2 p; p.x = f2bf(a[2 * k]); p.y = f2bf(a[2 * k + 1]);
      *(ushort2*)&sT[base + 2 * k] = p;
    }
    { ushort2 p; p.x = f2bf(a[22]); p.y = 0; *(ushort2*)&sT[base + 22] = p; }
    sL[chunk * NLIVE + row] = L;
  }
  __syncthreads();

  // ---- combine (wave 0 only): fold 16 chunk matrices, lane j = column j ----
  if (threadIdx.x < 64) {
    const int lane = threadIdx.x;
    const bool act = (lane < NLIVE);
    const int jc   = act ? lane : 0;

    const int tok0 = trow[0];
    const int flat0 = 168 + tok0;   // tp context (4,4,tok0)

    float v = act ? ws[WS_I + lane] * sBt[flat0 * 32 + lane] : 0.0f;
    float s = v;
    #pragma unroll
    for (int m = 1; m < 32; m <<= 1) s += __shfl_xor(s, m, 32);
    float ll = __logf(s);
    v = act ? v * __fdividef(1.0f, s) : 0.0f;

    for (int c = 0; c < CHUNKS; c++) {
      float Lj  = act ? sL[c * NLIVE + lane] : -3.0e38f;
      float key = (act && v > 0.0f) ? Lj : -3.0e38f;
      float mx = key;
      #pragma unroll
      for (int m = 1; m < 32; m <<= 1) mx = fmaxf(mx, __shfl_xor(mx, m, 32));
      float wgt = (act && v > 0.0f) ? v * __expf(Lj - mx) : 0.0f;

      float nv = 0.0f;
      #pragma unroll
      for (int r = 0; r < NLIVE; r++) {
        float wr = __shfl(wgt, r, 64);
        nv += wr * bf2f(sT[(c * NLIVE + r) * 24 + jc]);
      }
      float nva = act ? nv : 0.0f;
      float s2 = nva;
      #pragma unroll
      for (int m = 1; m < 32; m <<= 1) s2 += __shfl_xor(s2, m, 32);
      ll += mx + __logf(s2);
      v = act ? nv * __fdividef(1.0f, s2) : 0.0f;
    }

    if (lane == 0) out[seq] = ll;
  }
}

// ---------------------------------------------------------------------------
extern "C" void kernel_launch(void* const* d_in, const int* in_sizes, int n_in,
                              void* d_out, int out_size, void* d_ws, size_t ws_size,
                              hipStream_t stream) {
  const float* wT = (const float*)d_in[0];   // transition_kernel (10)
  const float* wE = (const float*)d_in[1];   // emission_kernel (5400)
  const float* wI = (const float*)d_in[2];   // init_kernel (25)
  const int* tokens = (const int*)d_in[3];   // (512, 2048) int32
  float* out = (float*)d_out;                // (512,) float32
  float* ws = (float*)d_ws;                  // ~28 KB used

  setup_kernel<<<26, 64, 0, stream>>>(wT, wE, wI, ws);
  rows_kernel<<<NSEQ, 512, 0, stream>>>(ws, tokens, out);
}